// Round 10
// baseline (559.271 us; speedup 1.0000x reference)
//
#include <hip/hip_runtime.h>
#include <hip/hip_bf16.h>

typedef __attribute__((ext_vector_type(8))) short short8;
typedef __attribute__((ext_vector_type(4))) float f32x4;
typedef __attribute__((ext_vector_type(4))) unsigned short u16x4;

#define D 256

static __device__ __forceinline__ unsigned short f2bf(float f) {
    union { __hip_bfloat16 h; unsigned short u; } v;
    v.h = __float2bfloat16(f);
    return v.u;
}
static __device__ __forceinline__ float bf2f(unsigned short h) {
    union { unsigned u; float f; } v; v.u = ((unsigned)h) << 16;
    return v.f;
}

// Pack W [K x 256] row-major f32 -> bf16 fragment-ready layout.
__global__ void pack_w_kernel(const float* __restrict__ W, unsigned short* __restrict__ dst,
                              int log2nkk, int total) {
    int p = blockIdx.x * blockDim.x + threadIdx.x;
    if (p >= total) return;
    int j     = p & 7;
    int lane  = (p >> 3) & 63;
    int kk    = (p >> 9) & ((1 << log2nkk) - 1);
    int ntile = p >> (9 + log2nkk);
    int k = kk * 32 + ((lane >> 4) * 8) + j;
    int n = ntile * 16 + (lane & 15);
    dst[p] = f2bf(W[k * D + n]);
}

__global__ void clear_pvr_kernel(int* __restrict__ pvr, int n) {
    int i = blockIdx.x * blockDim.x + threadIdx.x;
    if (i < n) pvr[i] = -1;
}

// inverse map: pvr[kidx[m]] = vidx[m]  (kidx unique -> deterministic)
__global__ void scatter_pvr_kernel(const int* __restrict__ kidx, const int* __restrict__ vidx,
                                   int* __restrict__ pvr, int m) {
    int i = blockIdx.x * blockDim.x + threadIdx.x;
    if (i < m) pvr[kidx[i]] = vidx[i];
}

// projall[r] = relu(cfg[r] @ Wu + bu) as bf16, row-major [N_CFG][256].
__global__ __launch_bounds__(256, 5) void projall_kernel(
    const float* __restrict__ cfg, const unsigned short* __restrict__ WuP,
    const float* __restrict__ bu, unsigned short* __restrict__ projall, int ncfg)
{
    __shared__ unsigned short Aub[64 * D];
    char* aubB = (char*)Aub;
    const int t = threadIdx.x, lane = t & 63, wid = t >> 6;
    const int lr = lane & 15, lk = lane >> 4;
    const int base = blockIdx.x * 64;

    #pragma unroll
    for (int i = 0; i < 16; ++i) {
        int row = wid * 16 + i;
        int r = base + row;
        f32x4 u = (f32x4){0.f, 0.f, 0.f, 0.f};
        if (r < ncfg) u = *(const f32x4*)(cfg + (size_t)r * D + lane * 4);
        int boff = (lane * 8) ^ ((row & 7) << 4);
        u16x4 hu;
        hu.x = f2bf(u.x); hu.y = f2bf(u.y); hu.z = f2bf(u.z); hu.w = f2bf(u.w);
        *(u16x4*)(aubB + row * 512 + boff) = hu;
    }
    __syncthreads();

    f32x4 acc[4][4];
    #pragma unroll
    for (int fm = 0; fm < 4; ++fm)
        #pragma unroll
        for (int fn = 0; fn < 4; ++fn)
            acc[fm][fn] = (f32x4){0.f, 0.f, 0.f, 0.f};

    #pragma unroll
    for (int kk = 0; kk < 8; ++kk) {
        short8 a[4], b[4];
        #pragma unroll
        for (int fm = 0; fm < 4; ++fm) {
            int row = fm * 16 + lr;
            int boff = (kk * 64 + lk * 16) ^ ((row & 7) << 4);
            a[fm] = *(const short8*)(aubB + row * 512 + boff);
        }
        #pragma unroll
        for (int fn = 0; fn < 4; ++fn) {
            int ntile = wid * 4 + fn;
            b[fn] = *(const short8*)(WuP + ((size_t)(ntile * 8 + kk) * 64 + lane) * 8);
        }
        #pragma unroll
        for (int fm = 0; fm < 4; ++fm)
            #pragma unroll
            for (int fn = 0; fn < 4; ++fn)
                acc[fm][fn] = __builtin_amdgcn_mfma_f32_16x16x32_bf16(a[fm], b[fn], acc[fm][fn], 0, 0, 0);
    }

    float bu4[4];
    #pragma unroll
    for (int fn = 0; fn < 4; ++fn) bu4[fn] = bu[wid * 64 + fn * 16 + lr];

    #pragma unroll
    for (int fm = 0; fm < 4; ++fm) {
        #pragma unroll
        for (int i = 0; i < 4; ++i) {
            int r = base + fm * 16 + lk * 4 + i;
            if (r >= ncfg) continue;
            #pragma unroll
            for (int fn = 0; fn < 4; ++fn) {
                float p = acc[fm][fn][i] + bu4[fn];
                p = p > 0.f ? p : 0.f;
                projall[(size_t)r * D + wid * 64 + fn * 16 + lr] = f2bf(p);
            }
        }
    }
}

// Output-centric streaming pass: walk ALL AST rows in order. prev reads and
// out writes are sequential; only 512B projall rows are gathered (L3-hot).
// Uncovered rows (pvr<0) pass state through exactly (f32 reload from L2).
// 1024 threads (16 waves), BM=64 rows/block, 2 blocks/CU, <=64 VGPR.
__global__ __launch_bounds__(1024, 8) void fused5_kernel(
    const float* __restrict__ prev, const unsigned short* __restrict__ projall,
    const int* __restrict__ pvr, const unsigned short* __restrict__ WgP,
    const float* __restrict__ bg, float* __restrict__ out, int nrows)
{
    __shared__ unsigned short Ast[64 * D];  // state bf16, swizzled 512B rows
    __shared__ unsigned short Apj[64 * D];  // proj  bf16, swizzled 512B rows
    char* astB = (char*)Ast;
    char* apjB = (char*)Apj;

    const int tid  = threadIdx.x;
    const int lane = tid & 63;
    const int wid  = tid >> 6;      // 0..15
    const int lr   = lane & 15;
    const int lk   = lane >> 4;
    const int base = blockIdx.x * 64;

    // ---- stage state: sequential full-row NT loads (streaming) ----
    #pragma unroll
    for (int i = 0; i < 4; ++i) {
        int row = wid * 4 + i;
        int r = base + row;
        f32x4 s = (f32x4){0.f, 0.f, 0.f, 0.f};
        if (r < nrows) s = __builtin_nontemporal_load((const f32x4*)(prev + (size_t)r * D) + lane);
        int boff = (lane * 8) ^ ((row & 7) << 4);
        u16x4 hs;
        hs.x = f2bf(s.x); hs.y = f2bf(s.y); hs.z = f2bf(s.z); hs.w = f2bf(s.w);
        *(u16x4*)(astB + row * 512 + boff) = hs;
    }
    // ---- stage proj: gathered 512B bf16 rows via inverse map (L3-hot) ----
    #pragma unroll
    for (int i = 0; i < 2; ++i) {
        int row = wid * 4 + i * 2 + (lane >> 5);
        int r = base + row;
        int pv = (r < nrows) ? pvr[r] : -1;
        int src = pv < 0 ? 0 : pv;
        short8 pvv = *(const short8*)(projall + (size_t)src * D + (lane & 31) * 8);
        int boff = ((lane & 31) * 16) ^ ((row & 7) << 4);
        *(short8*)(apjB + row * 512 + boff) = pvv;
    }
    __syncthreads();

    // ---- GEMM2: logits = [state, proj] @ Wg, K = 512; wave cols [wid*16, wid*16+16) ----
    f32x4 acc2[4];
    #pragma unroll
    for (int fm = 0; fm < 4; ++fm)
        acc2[fm] = (f32x4){0.f, 0.f, 0.f, 0.f};

    #pragma unroll
    for (int kk = 0; kk < 16; ++kk) {
        const char* Asrc = (kk < 8) ? astB : apjB;
        int kkl = kk & 7;
        short8 a[4], b;
        #pragma unroll
        for (int fm = 0; fm < 4; ++fm) {
            int row = fm * 16 + lr;
            int boff = (kkl * 64 + lk * 16) ^ ((row & 7) << 4);
            a[fm] = *(const short8*)(Asrc + row * 512 + boff);
        }
        b = *(const short8*)(WgP + ((size_t)(wid * 16 + kk) * 64 + lane) * 8);
        #pragma unroll
        for (int fm = 0; fm < 4; ++fm)
            acc2[fm] = __builtin_amdgcn_mfma_f32_16x16x32_bf16(a[fm], b, acc2[fm], 0, 0, 0);
    }

    // ---- epilogue: covered -> gated mix; uncovered -> exact f32 passthrough ----
    const float bg1 = bg[wid * 16 + lr];
    const int col = wid * 16 + lr;

    #pragma unroll
    for (int fm = 0; fm < 4; ++fm) {
        #pragma unroll
        for (int i = 0; i < 4; ++i) {
            int row = fm * 16 + lk * 4 + i;
            int r = base + row;
            if (r >= nrows) continue;
            int pv = pvr[r];
            float val;
            if (pv >= 0) {
                float x = acc2[fm][i] + bg1;
                float g = 1.f / (1.f + __expf(-x));
                int boff = (col * 2) ^ ((row & 7) << 4);
                float st = bf2f(*(const unsigned short*)(astB + row * 512 + boff));
                float pj = bf2f(*(const unsigned short*)(apjB + row * 512 + boff));
                val = g * st + (1.f - g) * pj;
            } else {
                val = prev[(size_t)r * D + col];   // L2-hot, exact copy
            }
            __builtin_nontemporal_store(val, out + (size_t)r * D + col);
        }
    }
}

extern "C" void kernel_launch(void* const* d_in, const int* in_sizes, int n_in,
                              void* d_out, int out_size, void* d_ws, size_t ws_size,
                              hipStream_t stream) {
    const float* prev = (const float*)d_in[0];
    const float* cfg  = (const float*)d_in[1];
    const int* kidx   = (const int*)d_in[2];
    const int* vidx   = (const int*)d_in[3];
    const float* Wu   = (const float*)d_in[4];
    const float* bu   = (const float*)d_in[5];
    const float* Wg   = (const float*)d_in[6];
    const float* bg   = (const float*)d_in[7];
    float* out = (float*)d_out;

    const int N_AST = in_sizes[0] / D;  // 500000
    const int N_CFG = in_sizes[1] / D;  // 100000
    const int M     = in_sizes[2];      // 400000

    unsigned short* WuP = (unsigned short*)d_ws;               // 128 KB
    unsigned short* WgP = WuP + 256 * 256;                     // 256 KB @128KB
    int* pvr = (int*)((char*)d_ws + (384 << 10));              // N_AST*4 = 2MB @384KB
    unsigned short* projall = (unsigned short*)((char*)d_ws + (4 << 20));  // 51.2MB @4MB

    const int totalWu = 256 * 256;
    const int totalWg = 512 * 256;
    const int ntiles  = (N_AST + 63) / 64;   // 7813

    pack_w_kernel<<<(totalWu + 255) / 256, 256, 0, stream>>>(Wu, WuP, 3, totalWu);
    pack_w_kernel<<<(totalWg + 255) / 256, 256, 0, stream>>>(Wg, WgP, 4, totalWg);
    clear_pvr_kernel<<<(N_AST + 255) / 256, 256, 0, stream>>>(pvr, N_AST);
    scatter_pvr_kernel<<<(M + 255) / 256, 256, 0, stream>>>(kidx, vidx, pvr, M);

    projall_kernel<<<(N_CFG + 63) / 64, 256, 0, stream>>>(cfg, WuP, bu, projall, N_CFG);
    fused5_kernel<<<ntiles, 1024, 0, stream>>>(prev, projall, pvr, WgP, bg, out, N_AST);
}